// Round 1
// baseline (5486.881 us; speedup 1.0000x reference)
//
#include <hip/hip_runtime.h>
#include <hip/hip_bf16.h>
#include <stdint.h>

#define N_RES 4096
#define BATCH 8
#define T_STEPS 256
#define VOCAB 32000
#define R_OUT 512
#define NNZ 131072

typedef short v8s __attribute__((ext_vector_type(8)));
typedef float v4f __attribute__((ext_vector_type(4)));

static __device__ __forceinline__ unsigned short f2bf(float f) {
    union { float f; unsigned u; } c; c.f = f;
    unsigned u = c.u;
    u = u + 0x7fffu + ((u >> 16) & 1u);
    return (unsigned short)(u >> 16);
}

// ---------------- init / CSR build ----------------

__global__ __launch_bounds__(256) void k_zero(float* p, int n) {
    int i = blockIdx.x * 256 + threadIdx.x;
    if (i < n) p[i] = 0.f;
}

__global__ __launch_bounds__(256) void k_hist(const int* __restrict__ rows,
                                              int* __restrict__ cnt) {
    int i = blockIdx.x * 256 + threadIdx.x;
    if (i < NNZ) atomicAdd(&cnt[rows[i]], 1);
}

__global__ __launch_bounds__(1024) void k_scan(const int* __restrict__ cnt,
                                               int* __restrict__ row_ptr,
                                               int* __restrict__ cursor) {
    __shared__ int sm[1024];
    int t = threadIdx.x;
    int base = t * 4;
    int c0 = cnt[base], c1 = cnt[base + 1], c2 = cnt[base + 2], c3 = cnt[base + 3];
    int s = c0 + c1 + c2 + c3;
    sm[t] = s;
    __syncthreads();
    for (int off = 1; off < 1024; off <<= 1) {
        int v = (t >= off) ? sm[t - off] : 0;
        __syncthreads();
        sm[t] += v;
        __syncthreads();
    }
    int run = sm[t] - s;   // exclusive prefix
    row_ptr[base] = run;     cursor[base] = run;     run += c0;
    row_ptr[base + 1] = run; cursor[base + 1] = run; run += c1;
    row_ptr[base + 2] = run; cursor[base + 2] = run; run += c2;
    row_ptr[base + 3] = run; cursor[base + 3] = run; run += c3;
    if (t == 1023) row_ptr[4096] = run;
}

__global__ __launch_bounds__(256) void k_fill(const int* __restrict__ rows,
                                              const int* __restrict__ cols,
                                              const float* __restrict__ vals,
                                              int* __restrict__ cursor,
                                              int* __restrict__ cols_s,
                                              float* __restrict__ vals_s) {
    int i = blockIdx.x * 256 + threadIdx.x;
    if (i < NNZ) {
        int r = rows[i];
        int p = atomicAdd(&cursor[r], 1);
        cols_s[p] = cols[i];
        vals_s[p] = vals[i];
    }
}

// ---------------- recurrence step ----------------

__global__ __launch_bounds__(256) void k_step(const float* __restrict__ h_cur,
                                              float* __restrict__ h_nxt,
                                              unsigned short* __restrict__ Hb,
                                              const float* __restrict__ W_in,
                                              const int* __restrict__ x,
                                              const int* __restrict__ row_ptr,
                                              const int* __restrict__ cols,
                                              const float* __restrict__ vals,
                                              const float* __restrict__ a,
                                              int t) {
    int i = blockIdx.x * 256 + threadIdx.x;           // 32768 threads
    int b = i >> 12;
    int n = i & (N_RES - 1);
    int tok = x[b * T_STEPS + t];
    float u = W_in[(size_t)tok * N_RES + n];
    const float* hb = h_cur + (b << 12);
    float acc = 0.f;
    int j0 = row_ptr[n], j1 = row_ptr[n + 1];
    for (int j = j0; j < j1; ++j)
        acc += vals[j] * hb[cols[j]];
    float pre = u + acc;
    pre = fminf(fmaxf(pre, -10.f), 10.f);
    float av = a[n];
    float hv = (1.f - av) * hb[n] + av * tanhf(pre);
    h_nxt[(b << 12) + n] = hv;
    Hb[((size_t)(b * T_STEPS + t) << 12) + n] = f2bf(hv);
}

// ---------------- convert A_w -> bf16 ----------------

__global__ __launch_bounds__(256) void k_cvt_aw(const float* __restrict__ src,
                                                unsigned short* __restrict__ dst,
                                                int n) {
    int i = (blockIdx.x * 256 + threadIdx.x) * 4;
    if (i < n) {
        float4 v = *reinterpret_cast<const float4*>(src + i);
        short4 o;
        o.x = (short)f2bf(v.x);
        o.y = (short)f2bf(v.y);
        o.z = (short)f2bf(v.z);
        o.w = (short)f2bf(v.w);
        *reinterpret_cast<short4*>(dst + i) = o;
    }
}

// ---------------- GEMM1: Rb(2048x512) = Hb(2048x4096,bf16) @ Bw^T (f32->bf16) ----------------
// grid: (x = N/128 = 4, y = M/128 = 16), block 512 (8 waves as 4 wm x 2 wn)

__global__ __launch_bounds__(512) void k_gemm1(const unsigned short* __restrict__ Hb,
                                               const float* __restrict__ Bw,
                                               float* __restrict__ Rb) {
    int lane = threadIdx.x & 63, wave = threadIdx.x >> 6;
    int wm = wave >> 1, wn = wave & 1;
    int row0 = blockIdx.y * 128;
    int col0 = blockIdx.x * 128 + wn * 64;
    int rA = lane & 15, kA = (lane >> 4) * 8;
    v4f acc[2][4];
    for (int s = 0; s < 2; ++s)
        for (int f = 0; f < 4; ++f)
            acc[s][f] = (v4f){0.f, 0.f, 0.f, 0.f};

    for (int k0 = 0; k0 < N_RES; k0 += 32) {
        v8s af[2];
#pragma unroll
        for (int s = 0; s < 2; ++s) {
            int r = row0 + (wm * 2 + s) * 16 + rA;
            af[s] = *reinterpret_cast<const v8s*>(Hb + (size_t)r * N_RES + k0 + kA);
        }
        v8s bf[4];
#pragma unroll
        for (int f = 0; f < 4; ++f) {
            int c = col0 + f * 16 + rA;
            const float* p = Bw + (size_t)c * N_RES + k0 + kA;
            float4 x0 = *reinterpret_cast<const float4*>(p);
            float4 x1 = *reinterpret_cast<const float4*>(p + 4);
            v8s t;
            t[0] = (short)f2bf(x0.x); t[1] = (short)f2bf(x0.y);
            t[2] = (short)f2bf(x0.z); t[3] = (short)f2bf(x0.w);
            t[4] = (short)f2bf(x1.x); t[5] = (short)f2bf(x1.y);
            t[6] = (short)f2bf(x1.z); t[7] = (short)f2bf(x1.w);
            bf[f] = t;
        }
#pragma unroll
        for (int s = 0; s < 2; ++s)
#pragma unroll
            for (int f = 0; f < 4; ++f)
                acc[s][f] = __builtin_amdgcn_mfma_f32_16x16x32_bf16(af[s], bf[f], acc[s][f], 0, 0, 0);
    }
#pragma unroll
    for (int s = 0; s < 2; ++s)
#pragma unroll
        for (int f = 0; f < 4; ++f) {
            int col = col0 + f * 16 + (lane & 15);
#pragma unroll
            for (int r = 0; r < 4; ++r) {
                int row = row0 + (wm * 2 + s) * 16 + (lane >> 4) * 4 + r;
                Rb[(size_t)row * R_OUT + col] = acc[s][f][r];
            }
        }
}

// ---------------- GEMM2: out(2048x32000) = Rb(f32->bf16) @ Awb^T + Ab ----------------
// grid: (x = M/256 = 8, y = N/128 = 250), block 512 (8 waves as 4 wm x 2 wn)

__global__ __launch_bounds__(512) void k_gemm2(const float* __restrict__ Rb,
                                               const unsigned short* __restrict__ Awb,
                                               const float* __restrict__ Ab,
                                               float* __restrict__ out) {
    int lane = threadIdx.x & 63, wave = threadIdx.x >> 6;
    int wm = wave >> 1, wn = wave & 1;
    int row0 = blockIdx.x * 256;
    int col0 = blockIdx.y * 128 + wn * 64;
    int rA = lane & 15, kA = (lane >> 4) * 8;
    v4f acc[4][4];
    for (int s = 0; s < 4; ++s)
        for (int f = 0; f < 4; ++f)
            acc[s][f] = (v4f){0.f, 0.f, 0.f, 0.f};

    for (int k0 = 0; k0 < R_OUT; k0 += 32) {
        v8s af[4];
#pragma unroll
        for (int s = 0; s < 4; ++s) {
            int r = row0 + (wm * 4 + s) * 16 + rA;
            const float* p = Rb + (size_t)r * R_OUT + k0 + kA;
            float4 x0 = *reinterpret_cast<const float4*>(p);
            float4 x1 = *reinterpret_cast<const float4*>(p + 4);
            v8s t;
            t[0] = (short)f2bf(x0.x); t[1] = (short)f2bf(x0.y);
            t[2] = (short)f2bf(x0.z); t[3] = (short)f2bf(x0.w);
            t[4] = (short)f2bf(x1.x); t[5] = (short)f2bf(x1.y);
            t[6] = (short)f2bf(x1.z); t[7] = (short)f2bf(x1.w);
            af[s] = t;
        }
        v8s bf[4];
#pragma unroll
        for (int f = 0; f < 4; ++f) {
            int c = col0 + f * 16 + rA;
            bf[f] = *reinterpret_cast<const v8s*>(Awb + (size_t)c * R_OUT + k0 + kA);
        }
#pragma unroll
        for (int s = 0; s < 4; ++s)
#pragma unroll
            for (int f = 0; f < 4; ++f)
                acc[s][f] = __builtin_amdgcn_mfma_f32_16x16x32_bf16(af[s], bf[f], acc[s][f], 0, 0, 0);
    }
#pragma unroll
    for (int f = 0; f < 4; ++f) {
        int col = col0 + f * 16 + (lane & 15);
        float bias = Ab[col];
#pragma unroll
        for (int s = 0; s < 4; ++s) {
#pragma unroll
            for (int r = 0; r < 4; ++r) {
                int row = row0 + (wm * 4 + s) * 16 + (lane >> 4) * 4 + r;
                out[(size_t)row * VOCAB + col] = acc[s][f][r] + bias;
            }
        }
    }
}

// ---------------- host launch ----------------

extern "C" void kernel_launch(void* const* d_in, const int* in_sizes, int n_in,
                              void* d_out, int out_size, void* d_ws, size_t ws_size,
                              hipStream_t stream) {
    const int*   x        = (const int*)d_in[0];
    const float* W_in     = (const float*)d_in[1];
    const int*   rec_rows = (const int*)d_in[2];
    const int*   rec_cols = (const int*)d_in[3];
    const float* rec_vals = (const float*)d_in[4];
    const float* a        = (const float*)d_in[5];
    const float* B_w      = (const float*)d_in[6];
    const float* A_w      = (const float*)d_in[7];
    const float* A_b      = (const float*)d_in[8];
    float* out = (float*)d_out;

    char* w = (char*)d_ws;
    size_t off = 0;
    auto alloc = [&](size_t bytes) { void* p = w + off; off = (off + bytes + 255) & ~(size_t)255; return p; };

    unsigned short* Hb     = (unsigned short*)alloc((size_t)2048 * N_RES * 2);   // 16.8 MB
    float*          Rb     = (float*)alloc((size_t)2048 * R_OUT * 4);            // 4 MB
    unsigned short* Awb    = (unsigned short*)alloc((size_t)VOCAB * R_OUT * 2);  // 32.8 MB
    float*          h0     = (float*)alloc((size_t)BATCH * N_RES * 4);           // 128 KB
    float*          h1     = (float*)alloc((size_t)BATCH * N_RES * 4);           // 128 KB
    int*            cnt    = (int*)alloc(4096 * 4);
    int*            rowptr = (int*)alloc(4097 * 4);
    int*            cursor = (int*)alloc(4096 * 4);
    int*            cols_s = (int*)alloc((size_t)NNZ * 4);
    float*          vals_s = (float*)alloc((size_t)NNZ * 4);

    // zero h0, h1, cnt (contiguous region from h0): 32768+32768+4096 = 69632 words
    // (h0/h1/cnt are consecutive allocations but padded; zero each individually)
    k_zero<<<(BATCH * N_RES + 255) / 256, 256, 0, stream>>>(h0, BATCH * N_RES);
    k_zero<<<(BATCH * N_RES + 255) / 256, 256, 0, stream>>>(h1, BATCH * N_RES);
    k_zero<<<(4096 + 255) / 256, 256, 0, stream>>>((float*)cnt, 4096);

    k_hist<<<(NNZ + 255) / 256, 256, 0, stream>>>(rec_rows, cnt);
    k_scan<<<1, 1024, 0, stream>>>(cnt, rowptr, cursor);
    k_fill<<<(NNZ + 255) / 256, 256, 0, stream>>>(rec_rows, rec_cols, rec_vals,
                                                  cursor, cols_s, vals_s);

    k_cvt_aw<<<(VOCAB * R_OUT / 4 + 255) / 256, 256, 0, stream>>>(A_w, Awb, VOCAB * R_OUT);

    for (int t = 0; t < T_STEPS; ++t) {
        const float* hc = (t & 1) ? h1 : h0;
        float*       hn = (t & 1) ? h0 : h1;
        k_step<<<(BATCH * N_RES) / 256, 256, 0, stream>>>(hc, hn, Hb, W_in, x,
                                                          rowptr, cols_s, vals_s, a, t);
    }

    k_gemm1<<<dim3(R_OUT / 128, 2048 / 128), 512, 0, stream>>>(Hb, B_w, Rb);
    k_gemm2<<<dim3(2048 / 256, VOCAB / 128), 512, 0, stream>>>(Rb, Awb, A_b, out);
}

// Round 2
// 3825.888 us; speedup vs baseline: 1.4341x; 1.4341x over previous
//
#include <hip/hip_runtime.h>
#include <hip/hip_bf16.h>
#include <stdint.h>

#define N_RES 4096
#define BATCH 8
#define T_STEPS 256
#define VOCAB 32000
#define R_OUT 512
#define NNZ 131072
#define NNZ_CAP 163840          // NNZ + 4096*7 padding headroom
#define NWG 64                  // 32 row-slices x 2 batch-halves
#define SLICES 32
#define ROWS_PS 128             // rows per slice
#define CSR_CAP 6144            // entries per slice in LDS (mean 4608, +23 sigma)

typedef _Float16 v8h __attribute__((ext_vector_type(8)));
typedef float v4f __attribute__((ext_vector_type(4)));

static __device__ __forceinline__ unsigned short f2h(float f) {
    _Float16 h = (_Float16)f;
    unsigned short u;
    __builtin_memcpy(&u, &h, 2);
    return u;
}
static __device__ __forceinline__ float h2f(unsigned short u) {
    _Float16 h;
    __builtin_memcpy(&h, &u, 2);
    return (float)h;
}

// ---------------- init / CSR build ----------------

__global__ __launch_bounds__(256) void k_zero(unsigned* p, int n) {
    int i = blockIdx.x * 256 + threadIdx.x;
    if (i < n) p[i] = 0u;
}

__global__ __launch_bounds__(256) void k_hist(const int* __restrict__ rows,
                                              int* __restrict__ cnt) {
    int i = blockIdx.x * 256 + threadIdx.x;
    if (i < NNZ) atomicAdd(&cnt[rows[i]], 1);
}

// padded scan: each row's span rounded up to multiple of 8
__global__ __launch_bounds__(1024) void k_scan(const int* __restrict__ cnt,
                                               int* __restrict__ row_ptr,
                                               int* __restrict__ cursor) {
    __shared__ int sm[1024];
    int t = threadIdx.x;
    int base = t * 4;
    int c0 = (cnt[base] + 7) & ~7;
    int c1 = (cnt[base + 1] + 7) & ~7;
    int c2 = (cnt[base + 2] + 7) & ~7;
    int c3 = (cnt[base + 3] + 7) & ~7;
    int s = c0 + c1 + c2 + c3;
    sm[t] = s;
    __syncthreads();
    for (int off = 1; off < 1024; off <<= 1) {
        int v = (t >= off) ? sm[t - off] : 0;
        __syncthreads();
        sm[t] += v;
        __syncthreads();
    }
    int run = sm[t] - s;
    row_ptr[base] = run;     cursor[base] = run;     run += c0;
    row_ptr[base + 1] = run; cursor[base + 1] = run; run += c1;
    row_ptr[base + 2] = run; cursor[base + 2] = run; run += c2;
    row_ptr[base + 3] = run; cursor[base + 3] = run; run += c3;
    if (t == 1023) row_ptr[4096] = run;
}

// packed CSR entry: (col*8)<<16 | f16(val)   (col*8 = byte offset in 32KB half-plane)
__global__ __launch_bounds__(256) void k_fill(const int* __restrict__ rows,
                                              const int* __restrict__ cols,
                                              const float* __restrict__ vals,
                                              int* __restrict__ cursor,
                                              unsigned* __restrict__ csr) {
    int i = blockIdx.x * 256 + threadIdx.x;
    if (i < NNZ) {
        int r = rows[i];
        int p = atomicAdd(&cursor[r], 1);
        unsigned pack = ((unsigned)(cols[i] * 8) << 16) | (unsigned)f2h(vals[i]);
        csr[p] = pack;
    }
}

// ---------------- W_in pre-gather: U8[t][n][8] f16 ----------------

__global__ __launch_bounds__(256) void k_prep_u(const float* __restrict__ W_in,
                                                const int* __restrict__ x,
                                                unsigned short* __restrict__ U8) {
    int i = blockIdx.x * 256 + threadIdx.x;   // T*N threads
    int t = i >> 12;
    int n = i & (N_RES - 1);
    unsigned short u[8];
#pragma unroll
    for (int b = 0; b < 8; ++b) {
        int tok = x[b * T_STEPS + t];
        u[b] = f2h(W_in[(size_t)tok * N_RES + n]);
    }
    *reinterpret_cast<uint4*>(U8 + (size_t)i * 8) = *reinterpret_cast<uint4*>(u);
}

// ---------------- persistent recurrence: 64 WGs x 128 threads ----------------
// WG w: slice = w>>1 (rows slice*128 .. +128), half = w&1 (batches half*4 .. +4)
// LDS: h half-plane [4096][4 f16] = 32KB at 0; CSR slice (<=6144 u32) at 32768.
// Global h8g: [parity][plane(2)][4096][4 f16] = 2 x 64KB.

__global__ __launch_bounds__(128) void k_steps(const int* __restrict__ rowptr,
                                               const unsigned* __restrict__ csr,
                                               const unsigned short* __restrict__ U8,
                                               const float* __restrict__ a,
                                               unsigned short* __restrict__ Hb,
                                               unsigned short* __restrict__ h8g,
                                               unsigned* __restrict__ ctr) {
    __shared__ char lds[32768 + CSR_CAP * 4];
    char* hplane = lds;
    unsigned* lcsr = (unsigned*)(lds + 32768);

    int w = blockIdx.x;
    int tid = threadIdx.x;
    int slice = w >> 1;
    int half = w & 1;
    int gr = slice * ROWS_PS + tid;          // this thread's reservoir row

    // load CSR slice into LDS
    int j0 = rowptr[slice * ROWS_PS];
    int j1 = rowptr[slice * ROWS_PS + ROWS_PS];
    int cntE = j1 - j0;
    if (cntE > CSR_CAP) cntE = CSR_CAP;      // P ~ 0, memory safety only
    for (int k = tid; k < cntE; k += 128) lcsr[k] = csr[j0 + k];
    // zero h half-plane (h_0 = 0)
    for (int k = tid; k < 8192; k += 128) ((unsigned*)hplane)[k] = 0u;

    int js = rowptr[gr] - j0;
    int je = rowptr[gr + 1] - j0;
    if (je > CSR_CAP) je = CSR_CAP;
    float av = a[gr];
    float one_m_av = 1.f - av;
    __syncthreads();

    char* h8g_b = (char*)h8g;

    for (int t = 0; t < T_STEPS; ++t) {
        // input projection (independent of LDS -> issues early)
        ushort4 uu = *reinterpret_cast<const ushort4*>(
            U8 + ((size_t)(t << 12) + gr) * 8 + half * 4);

        v4f acc = {0.f, 0.f, 0.f, 0.f};
        for (int j = js; j < je; j += 8) {
            unsigned e[8];
            *reinterpret_cast<uint4*>(e)     = *reinterpret_cast<const uint4*>(lcsr + j);
            *reinterpret_cast<uint4*>(e + 4) = *reinterpret_cast<const uint4*>(lcsr + j + 4);
            uint2 g[8];
#pragma unroll
            for (int q = 0; q < 8; ++q)
                g[q] = *reinterpret_cast<const uint2*>(hplane + (e[q] >> 16));
#pragma unroll
            for (int q = 0; q < 8; ++q) {
                float v = h2f((unsigned short)(e[q] & 0xffffu));
                acc.x += v * h2f((unsigned short)(g[q].x & 0xffffu));
                acc.y += v * h2f((unsigned short)(g[q].x >> 16));
                acc.z += v * h2f((unsigned short)(g[q].y & 0xffffu));
                acc.w += v * h2f((unsigned short)(g[q].y >> 16));
            }
        }

        // h_old for own row (4 batches of our half)
        uint2 ho = *reinterpret_cast<const uint2*>(hplane + gr * 8);
        float hold[4] = { h2f((unsigned short)(ho.x & 0xffffu)),
                          h2f((unsigned short)(ho.x >> 16)),
                          h2f((unsigned short)(ho.y & 0xffffu)),
                          h2f((unsigned short)(ho.y >> 16)) };
        float uf[4] = { h2f(uu.x), h2f(uu.y), h2f(uu.z), h2f(uu.w) };
        float av_[4] = { acc.x, acc.y, acc.z, acc.w };
        unsigned short hv[4];
#pragma unroll
        for (int i = 0; i < 4; ++i) {
            float pre = uf[i] + av_[i];
            pre = fminf(fmaxf(pre, -10.f), 10.f);
            float ex = __expf(2.f * pre);
            float th = 1.f - 2.f / (ex + 1.f);
            float hn = one_m_av * hold[i] + av * th;
            hv[i] = f2h(hn);
            // history for GEMM1: Hb[(b*T+t)][n]
            Hb[((size_t)((half * 4 + i) * T_STEPS + t) << 12) + gr] = hv[i];
        }
        int par = t & 1;
        *reinterpret_cast<uint2*>(h8g_b + par * 65536 + half * 32768 + gr * 8) =
            *reinterpret_cast<uint2*>(hv);

        if (t == T_STEPS - 1) break;

        // ---- device barrier: release, arrive, spin, acquire ----
        __threadfence();                     // release: drain stores, wb L2
        __syncthreads();
        if (tid == 0) {
            __hip_atomic_fetch_add(ctr, 1u, __ATOMIC_RELAXED, __HIP_MEMORY_SCOPE_AGENT);
            unsigned target = (unsigned)(t + 1) * NWG;
            while (__hip_atomic_load(ctr, __ATOMIC_RELAXED, __HIP_MEMORY_SCOPE_AGENT) < target)
                __builtin_amdgcn_s_sleep(1);
        }
        __syncthreads();
        __threadfence();                     // acquire: invalidate L1/L2

        // refill own half-plane from global (all slices' fresh h)
        const uint4* src = (const uint4*)(h8g_b + par * 65536 + half * 32768);
        uint4* dst = (uint4*)hplane;
        for (int k = tid; k < 2048; k += 128) dst[k] = src[k];
        __syncthreads();
    }
}

// ---------------- GEMM1: Rbh(2048x512,f16) = Hb(2048x4096,f16) @ Bw^T ----------------

__global__ __launch_bounds__(512) void k_gemm1(const unsigned short* __restrict__ Hb,
                                               const float* __restrict__ Bw,
                                               unsigned short* __restrict__ Rbh) {
    int lane = threadIdx.x & 63, wave = threadIdx.x >> 6;
    int wm = wave >> 1, wn = wave & 1;
    int row0 = blockIdx.y * 128;
    int col0 = blockIdx.x * 128 + wn * 64;
    int rA = lane & 15, kA = (lane >> 4) * 8;
    v4f acc[2][4];
    for (int s = 0; s < 2; ++s)
        for (int f = 0; f < 4; ++f)
            acc[s][f] = (v4f){0.f, 0.f, 0.f, 0.f};

    for (int k0 = 0; k0 < N_RES; k0 += 32) {
        v8h af[2];
#pragma unroll
        for (int s = 0; s < 2; ++s) {
            int r = row0 + (wm * 2 + s) * 16 + rA;
            af[s] = *reinterpret_cast<const v8h*>(Hb + (size_t)r * N_RES + k0 + kA);
        }
        v8h bf[4];
#pragma unroll
        for (int f = 0; f < 4; ++f) {
            int c = col0 + f * 16 + rA;
            const float* p = Bw + (size_t)c * N_RES + k0 + kA;
            float4 x0 = *reinterpret_cast<const float4*>(p);
            float4 x1 = *reinterpret_cast<const float4*>(p + 4);
            v8h tv;
            tv[0] = (_Float16)x0.x; tv[1] = (_Float16)x0.y;
            tv[2] = (_Float16)x0.z; tv[3] = (_Float16)x0.w;
            tv[4] = (_Float16)x1.x; tv[5] = (_Float16)x1.y;
            tv[6] = (_Float16)x1.z; tv[7] = (_Float16)x1.w;
            bf[f] = tv;
        }
#pragma unroll
        for (int s = 0; s < 2; ++s)
#pragma unroll
            for (int f = 0; f < 4; ++f)
                acc[s][f] = __builtin_amdgcn_mfma_f32_16x16x32_f16(af[s], bf[f], acc[s][f], 0, 0, 0);
    }
#pragma unroll
    for (int s = 0; s < 2; ++s)
#pragma unroll
        for (int f = 0; f < 4; ++f) {
            int col = col0 + f * 16 + (lane & 15);
#pragma unroll
            for (int r = 0; r < 4; ++r) {
                int row = row0 + (wm * 2 + s) * 16 + (lane >> 4) * 4 + r;
                Rbh[(size_t)row * R_OUT + col] = f2h(acc[s][f][r]);
            }
        }
}

// ---------------- GEMM2: out(2048x32000,f32) = Rbh(f16) @ A_w^T + Ab ----------------

__global__ __launch_bounds__(512) void k_gemm2(const unsigned short* __restrict__ Rbh,
                                               const float* __restrict__ Aw,
                                               const float* __restrict__ Ab,
                                               float* __restrict__ out) {
    int lane = threadIdx.x & 63, wave = threadIdx.x >> 6;
    int wm = wave >> 1, wn = wave & 1;
    int row0 = blockIdx.x * 256;
    int col0 = blockIdx.y * 128 + wn * 64;
    int rA = lane & 15, kA = (lane >> 4) * 8;
    v4f acc[4][4];
    for (int s = 0; s < 4; ++s)
        for (int f = 0; f < 4; ++f)
            acc[s][f] = (v4f){0.f, 0.f, 0.f, 0.f};

    for (int k0 = 0; k0 < R_OUT; k0 += 32) {
        v8h af[4];
#pragma unroll
        for (int s = 0; s < 4; ++s) {
            int r = row0 + (wm * 4 + s) * 16 + rA;
            af[s] = *reinterpret_cast<const v8h*>(Rbh + (size_t)r * R_OUT + k0 + kA);
        }
        v8h bf[4];
#pragma unroll
        for (int f = 0; f < 4; ++f) {
            int c = col0 + f * 16 + rA;
            const float* p = Aw + (size_t)c * R_OUT + k0 + kA;
            float4 x0 = *reinterpret_cast<const float4*>(p);
            float4 x1 = *reinterpret_cast<const float4*>(p + 4);
            v8h tv;
            tv[0] = (_Float16)x0.x; tv[1] = (_Float16)x0.y;
            tv[2] = (_Float16)x0.z; tv[3] = (_Float16)x0.w;
            tv[4] = (_Float16)x1.x; tv[5] = (_Float16)x1.y;
            tv[6] = (_Float16)x1.z; tv[7] = (_Float16)x1.w;
            bf[f] = tv;
        }
#pragma unroll
        for (int s = 0; s < 4; ++s)
#pragma unroll
            for (int f = 0; f < 4; ++f)
                acc[s][f] = __builtin_amdgcn_mfma_f32_16x16x32_f16(af[s], bf[f], acc[s][f], 0, 0, 0);
    }
#pragma unroll
    for (int f = 0; f < 4; ++f) {
        int col = col0 + f * 16 + (lane & 15);
        float bias = Ab[col];
#pragma unroll
        for (int s = 0; s < 4; ++s) {
#pragma unroll
            for (int r = 0; r < 4; ++r) {
                int row = row0 + (wm * 4 + s) * 16 + (lane >> 4) * 4 + r;
                out[(size_t)row * VOCAB + col] = acc[s][f][r] + bias;
            }
        }
    }
}

// ---------------- host launch ----------------

extern "C" void kernel_launch(void* const* d_in, const int* in_sizes, int n_in,
                              void* d_out, int out_size, void* d_ws, size_t ws_size,
                              hipStream_t stream) {
    const int*   x        = (const int*)d_in[0];
    const float* W_in     = (const float*)d_in[1];
    const int*   rec_rows = (const int*)d_in[2];
    const int*   rec_cols = (const int*)d_in[3];
    const float* rec_vals = (const float*)d_in[4];
    const float* a        = (const float*)d_in[5];
    const float* B_w      = (const float*)d_in[6];
    const float* A_w      = (const float*)d_in[7];
    const float* A_b      = (const float*)d_in[8];
    float* out = (float*)d_out;

    char* w = (char*)d_ws;
    size_t off = 0;
    auto alloc = [&](size_t bytes) { void* p = w + off; off = (off + bytes + 255) & ~(size_t)255; return p; };

    unsigned short* Hb     = (unsigned short*)alloc((size_t)2048 * N_RES * 2);  // 16.8 MB
    unsigned short* U8     = (unsigned short*)alloc((size_t)T_STEPS * N_RES * 8 * 2); // 16.8 MB
    unsigned short* Rbh    = (unsigned short*)alloc((size_t)2048 * R_OUT * 2);  // 2.1 MB
    unsigned*       csr    = (unsigned*)alloc((size_t)NNZ_CAP * 4);             // 655 KB
    int*            rowptr = (int*)alloc(4097 * 4);
    int*            cnt    = (int*)alloc(4096 * 4);
    int*            cursor = (int*)alloc(4096 * 4);
    unsigned short* h8g    = (unsigned short*)alloc(2 * 65536);                 // 128 KB
    unsigned*       ctr    = (unsigned*)alloc(256);

    k_zero<<<(NNZ_CAP + 255) / 256, 256, 0, stream>>>(csr, NNZ_CAP);
    k_zero<<<(4096 + 255) / 256, 256, 0, stream>>>((unsigned*)cnt, 4096);
    k_zero<<<1, 256, 0, stream>>>(ctr, 1);

    k_hist<<<(NNZ + 255) / 256, 256, 0, stream>>>(rec_rows, cnt);
    k_scan<<<1, 1024, 0, stream>>>(cnt, rowptr, cursor);
    k_fill<<<(NNZ + 255) / 256, 256, 0, stream>>>(rec_rows, rec_cols, rec_vals, cursor, csr);

    k_prep_u<<<(T_STEPS * N_RES) / 256, 256, 0, stream>>>(W_in, x, U8);

    k_steps<<<NWG, 128, 0, stream>>>(rowptr, csr, U8, a, Hb, h8g, ctr);

    k_gemm1<<<dim3(R_OUT / 128, 2048 / 128), 512, 0, stream>>>(Hb, B_w, Rbh);
    k_gemm2<<<dim3(2048 / 256, VOCAB / 128), 512, 0, stream>>>(Rbh, A_w, A_b, out);
}

// Round 3
// 1501.350 us; speedup vs baseline: 3.6546x; 2.5483x over previous
//
#include <hip/hip_runtime.h>
#include <hip/hip_bf16.h>
#include <stdint.h>

#define N_RES 4096
#define BATCH 8
#define T_STEPS 256
#define VOCAB 32000
#define R_OUT 512
#define NNZ 131072
#define NNZ_CAP 163840
#define TEAMS 8             // one per batch
#define SLICES 16           // WGs per team
#define ROWS_PS 256         // rows per WG
#define NWG (TEAMS*SLICES)  // 128
#define CSR_CAP 10240       // entries per slice in LDS (mean ~9088, +11 sigma)

typedef _Float16 v8h __attribute__((ext_vector_type(8)));
typedef float v4f __attribute__((ext_vector_type(4)));

static __device__ __forceinline__ unsigned short f2h(float f) {
    _Float16 h = (_Float16)f;
    unsigned short u;
    __builtin_memcpy(&u, &h, 2);
    return u;
}
static __device__ __forceinline__ float h2f(unsigned short u) {
    _Float16 h;
    __builtin_memcpy(&h, &u, 2);
    return (float)h;
}

// ---------------- init / CSR build ----------------

__global__ __launch_bounds__(256) void k_zero(unsigned* p, int n) {
    int i = blockIdx.x * 256 + threadIdx.x;
    if (i < n) p[i] = 0u;
}

__global__ __launch_bounds__(256) void k_hist(const int* __restrict__ rows,
                                              int* __restrict__ cnt) {
    int i = blockIdx.x * 256 + threadIdx.x;
    if (i < NNZ) atomicAdd(&cnt[rows[i]], 1);
}

// padded scan: each row's span rounded up to multiple of 8
__global__ __launch_bounds__(1024) void k_scan(const int* __restrict__ cnt,
                                               int* __restrict__ row_ptr,
                                               int* __restrict__ cursor) {
    __shared__ int sm[1024];
    int t = threadIdx.x;
    int base = t * 4;
    int c0 = (cnt[base] + 7) & ~7;
    int c1 = (cnt[base + 1] + 7) & ~7;
    int c2 = (cnt[base + 2] + 7) & ~7;
    int c3 = (cnt[base + 3] + 7) & ~7;
    int s = c0 + c1 + c2 + c3;
    sm[t] = s;
    __syncthreads();
    for (int off = 1; off < 1024; off <<= 1) {
        int v = (t >= off) ? sm[t - off] : 0;
        __syncthreads();
        sm[t] += v;
        __syncthreads();
    }
    int run = sm[t] - s;
    row_ptr[base] = run;     cursor[base] = run;     run += c0;
    row_ptr[base + 1] = run; cursor[base + 1] = run; run += c1;
    row_ptr[base + 2] = run; cursor[base + 2] = run; run += c2;
    row_ptr[base + 3] = run; cursor[base + 3] = run; run += c3;
    if (t == 1023) row_ptr[4096] = run;
}

// packed CSR entry: swizzled plane byte-offset in hi16, f16 value in lo16.
// plane index p(col) = ((col&15)<<8) | (col>>4); byte off = p*4.
__global__ __launch_bounds__(256) void k_fill(const int* __restrict__ rows,
                                              const int* __restrict__ cols,
                                              const float* __restrict__ vals,
                                              int* __restrict__ cursor,
                                              unsigned* __restrict__ csr) {
    int i = blockIdx.x * 256 + threadIdx.x;
    if (i < NNZ) {
        int r = rows[i];
        int c = cols[i];
        int p = atomicAdd(&cursor[r], 1);
        unsigned off = ((unsigned)(c & 15) << 10) | ((unsigned)(c >> 4) << 2);
        csr[p] = (off << 16) | (unsigned)f2h(vals[i]);
    }
}

// ---------------- f32 -> f16 convert (for B_w, A_w) ----------------

__global__ __launch_bounds__(256) void k_cvt(const float* __restrict__ src,
                                             unsigned short* __restrict__ dst, int n) {
    int i = (blockIdx.x * 256 + threadIdx.x) * 8;
    if (i < n) {
        float4 a0 = *reinterpret_cast<const float4*>(src + i);
        float4 a1 = *reinterpret_cast<const float4*>(src + i + 4);
        unsigned short o[8] = { f2h(a0.x), f2h(a0.y), f2h(a0.z), f2h(a0.w),
                                f2h(a1.x), f2h(a1.y), f2h(a1.z), f2h(a1.w) };
        *reinterpret_cast<uint4*>(dst + i) = *reinterpret_cast<const uint4*>(o);
    }
}

// ---------------- persistent recurrence ----------------
// 128 WGs x 256 threads. team = wg&7 (batch), slice = wg>>3 (256 rows).
// Per-team exchange: hx[par][team][4096 f16] published as u64 chunks via
// relaxed agent atomics; per-WG epoch flag (128B apart) after vmcnt(0).
// LDS h-plane is f32, bank-swizzled; swizzle baked into CSR offsets.

__global__ __launch_bounds__(256) void k_steps(const int* __restrict__ rowptr,
                                               const unsigned* __restrict__ csr,
                                               const float* __restrict__ W_in,
                                               const int* __restrict__ x,
                                               const float* __restrict__ a,
                                               unsigned short* __restrict__ Hb,
                                               unsigned long long* __restrict__ hx,
                                               unsigned* __restrict__ flags) {
    __shared__ float plane[4096];                       // 16 KB, swizzled
    __shared__ __align__(16) unsigned lcsr[CSR_CAP];    // 40 KB
    __shared__ unsigned long long stage64[64];          // 512 B
    __shared__ int ltok[T_STEPS];                       // 1 KB

    int wg = blockIdx.x;
    int tid = threadIdx.x;
    int team = wg & 7;
    int slice = wg >> 3;
    int r_own = slice * ROWS_PS + tid;

    ltok[tid] = x[team * T_STEPS + tid];

    int j0 = rowptr[slice * ROWS_PS];
    int j1 = rowptr[slice * ROWS_PS + ROWS_PS];
    int cntE = j1 - j0;
    if (cntE > CSR_CAP) cntE = CSR_CAP;
    {
        const uint4* src = reinterpret_cast<const uint4*>(csr + j0);
        int n4 = cntE >> 2;
        for (int k = tid; k < n4; k += 256)
            reinterpret_cast<uint4*>(lcsr)[k] = src[k];
    }
    for (int k = tid; k < 4096; k += 256) plane[k] = 0.f;

    int js = rowptr[r_own] - j0;
    int je = rowptr[r_own + 1] - j0;
    if (js > CSR_CAP) js = CSR_CAP;
    if (je > CSR_CAP) je = CSR_CAP;
    float av = a[r_own];
    float oma = 1.f - av;
    int pown = ((r_own & 15) << 8) | (r_own >> 4);
    __syncthreads();

    float u_cur = W_in[(size_t)ltok[0] * N_RES + r_own];

    for (int t = 0; t < T_STEPS; ++t) {
        float u_nxt = 0.f;
        if (t + 1 < T_STEPS)
            u_nxt = W_in[(size_t)ltok[t + 1] * N_RES + r_own];   // long shadow

        float acc = 0.f;
        for (int j = js; j < je; j += 8) {
            uint4 e0 = *reinterpret_cast<const uint4*>(lcsr + j);
            uint4 e1 = *reinterpret_cast<const uint4*>(lcsr + j + 4);
            unsigned ee[8] = { e0.x, e0.y, e0.z, e0.w, e1.x, e1.y, e1.z, e1.w };
#pragma unroll
            for (int q = 0; q < 8; ++q) {
                float g = *reinterpret_cast<const float*>(
                    reinterpret_cast<const char*>(plane) + (ee[q] >> 16));
                acc += h2f((unsigned short)(ee[q] & 0xffffu)) * g;
            }
        }
        float hold = plane[pown];
        float pre = u_cur + acc;
        pre = fminf(fmaxf(pre, -10.f), 10.f);
        float ex = __expf(2.f * pre);
        float th = 1.f - 2.f / (ex + 1.f);
        float hv = oma * hold + av * th;
        unsigned short hv16 = f2h(hv);
        Hb[((size_t)(team * T_STEPS + t) << 12) + r_own] = hv16;
        u_cur = u_nxt;

        if (t == T_STEPS - 1) break;

        reinterpret_cast<unsigned short*>(stage64)[tid] = hv16;
        __syncthreads();
        int par = t & 1;
        unsigned long long* base = hx + ((size_t)(par * TEAMS + team)) * 1024;
        if (tid < 64) {
            unsigned long long d = stage64[tid];
            __hip_atomic_store(base + slice * 64 + tid, d,
                               __ATOMIC_RELAXED, __HIP_MEMORY_SCOPE_AGENT);
        }
        asm volatile("s_waitcnt vmcnt(0)" ::: "memory");
        __syncthreads();
        if (tid == 0)
            __hip_atomic_store(flags + (team * SLICES + slice) * 32, (unsigned)(t + 1),
                               __ATOMIC_RELAXED, __HIP_MEMORY_SCOPE_AGENT);
        if (tid < SLICES) {
            const unsigned* fp = flags + (team * SLICES + tid) * 32;
            while (__hip_atomic_load(fp, __ATOMIC_RELAXED,
                                     __HIP_MEMORY_SCOPE_AGENT) < (unsigned)(t + 1)) {}
        }
        __syncthreads();
        // pull fresh 8KB team plane, convert to swizzled f32
        const unsigned long long* src = base + tid * 4;
#pragma unroll
        for (int k = 0; k < 4; ++k) {
            unsigned long long d = __hip_atomic_load(src + k, __ATOMIC_RELAXED,
                                                     __HIP_MEMORY_SCOPE_AGENT);
            int jb = k * 4;
            plane[((jb + 0) << 8) | tid] = h2f((unsigned short)(d & 0xffffu));
            plane[((jb + 1) << 8) | tid] = h2f((unsigned short)((d >> 16) & 0xffffu));
            plane[((jb + 2) << 8) | tid] = h2f((unsigned short)((d >> 32) & 0xffffu));
            plane[((jb + 3) << 8) | tid] = h2f((unsigned short)((d >> 48) & 0xffffu));
        }
        __syncthreads();
    }
}

// ---------------- GEMM1: Rbh(2048x512,f16) = Hb(2048x4096,f16) @ Bwh^T ----------------

__global__ __launch_bounds__(512) void k_gemm1(const unsigned short* __restrict__ Hb,
                                               const unsigned short* __restrict__ Bwh,
                                               unsigned short* __restrict__ Rbh) {
    int lane = threadIdx.x & 63, wave = threadIdx.x >> 6;
    int wm = wave >> 1, wn = wave & 1;
    int row0 = blockIdx.y * 128;
    int col0 = blockIdx.x * 128 + wn * 64;
    int rA = lane & 15, kA = (lane >> 4) * 8;
    v4f acc[2][4];
    for (int s = 0; s < 2; ++s)
        for (int f = 0; f < 4; ++f)
            acc[s][f] = (v4f){0.f, 0.f, 0.f, 0.f};

    for (int k0 = 0; k0 < N_RES; k0 += 32) {
        v8h af[2];
#pragma unroll
        for (int s = 0; s < 2; ++s) {
            int r = row0 + (wm * 2 + s) * 16 + rA;
            af[s] = *reinterpret_cast<const v8h*>(Hb + (size_t)r * N_RES + k0 + kA);
        }
        v8h bf[4];
#pragma unroll
        for (int f = 0; f < 4; ++f) {
            int c = col0 + f * 16 + rA;
            bf[f] = *reinterpret_cast<const v8h*>(Bwh + (size_t)c * N_RES + k0 + kA);
        }
#pragma unroll
        for (int s = 0; s < 2; ++s)
#pragma unroll
            for (int f = 0; f < 4; ++f)
                acc[s][f] = __builtin_amdgcn_mfma_f32_16x16x32_f16(af[s], bf[f], acc[s][f], 0, 0, 0);
    }
#pragma unroll
    for (int s = 0; s < 2; ++s)
#pragma unroll
        for (int f = 0; f < 4; ++f) {
            int col = col0 + f * 16 + (lane & 15);
#pragma unroll
            for (int r = 0; r < 4; ++r) {
                int row = row0 + (wm * 2 + s) * 16 + (lane >> 4) * 4 + r;
                Rbh[(size_t)row * R_OUT + col] = f2h(acc[s][f][r]);
            }
        }
}

// ---------------- GEMM2: out(2048x32000,f32) = Rbh(f16) @ Awh^T + Ab ----------------

__global__ __launch_bounds__(512) void k_gemm2(const unsigned short* __restrict__ Rbh,
                                               const unsigned short* __restrict__ Awh,
                                               const float* __restrict__ Ab,
                                               float* __restrict__ out) {
    int lane = threadIdx.x & 63, wave = threadIdx.x >> 6;
    int wm = wave >> 1, wn = wave & 1;
    int row0 = blockIdx.x * 256;
    int col0 = blockIdx.y * 128 + wn * 64;
    int rA = lane & 15, kA = (lane >> 4) * 8;
    v4f acc[4][4];
    for (int s = 0; s < 4; ++s)
        for (int f = 0; f < 4; ++f)
            acc[s][f] = (v4f){0.f, 0.f, 0.f, 0.f};

    for (int k0 = 0; k0 < R_OUT; k0 += 32) {
        v8h af[4];
#pragma unroll
        for (int s = 0; s < 4; ++s) {
            int r = row0 + (wm * 4 + s) * 16 + rA;
            af[s] = *reinterpret_cast<const v8h*>(Rbh + (size_t)r * R_OUT + k0 + kA);
        }
        v8h bf[4];
#pragma unroll
        for (int f = 0; f < 4; ++f) {
            int c = col0 + f * 16 + rA;
            bf[f] = *reinterpret_cast<const v8h*>(Awh + (size_t)c * R_OUT + k0 + kA);
        }
#pragma unroll
        for (int s = 0; s < 4; ++s)
#pragma unroll
            for (int f = 0; f < 4; ++f)
                acc[s][f] = __builtin_amdgcn_mfma_f32_16x16x32_f16(af[s], bf[f], acc[s][f], 0, 0, 0);
    }
#pragma unroll
    for (int f = 0; f < 4; ++f) {
        int col = col0 + f * 16 + (lane & 15);
        float bias = Ab[col];
#pragma unroll
        for (int s = 0; s < 4; ++s) {
#pragma unroll
            for (int r = 0; r < 4; ++r) {
                int row = row0 + (wm * 4 + s) * 16 + (lane >> 4) * 4 + r;
                out[(size_t)row * VOCAB + col] = acc[s][f][r] + bias;
            }
        }
    }
}

// ---------------- host launch ----------------

extern "C" void kernel_launch(void* const* d_in, const int* in_sizes, int n_in,
                              void* d_out, int out_size, void* d_ws, size_t ws_size,
                              hipStream_t stream) {
    const int*   x        = (const int*)d_in[0];
    const float* W_in     = (const float*)d_in[1];
    const int*   rec_rows = (const int*)d_in[2];
    const int*   rec_cols = (const int*)d_in[3];
    const float* rec_vals = (const float*)d_in[4];
    const float* a        = (const float*)d_in[5];
    const float* B_w      = (const float*)d_in[6];
    const float* A_w      = (const float*)d_in[7];
    const float* A_b      = (const float*)d_in[8];
    float* out = (float*)d_out;

    char* w = (char*)d_ws;
    size_t off = 0;
    auto alloc = [&](size_t bytes) { void* p = w + off; off = (off + bytes + 255) & ~(size_t)255; return p; };

    unsigned short* Hb     = (unsigned short*)alloc((size_t)2048 * N_RES * 2);   // 16.8 MB
    unsigned short* Rbh    = (unsigned short*)alloc((size_t)2048 * R_OUT * 2);   // 2.1 MB
    unsigned short* Bwh    = (unsigned short*)alloc((size_t)R_OUT * N_RES * 2);  // 4.2 MB
    unsigned short* Awh    = (unsigned short*)alloc((size_t)VOCAB * R_OUT * 2);  // 32.8 MB
    unsigned*       csr    = (unsigned*)alloc((size_t)NNZ_CAP * 4);              // 655 KB
    int*            rowptr = (int*)alloc(4097 * 4);
    int*            cnt    = (int*)alloc(4096 * 4);
    int*            cursor = (int*)alloc(4096 * 4);
    unsigned long long* hx = (unsigned long long*)alloc(2 * TEAMS * 1024 * 8);   // 128 KB
    unsigned*       flags  = (unsigned*)alloc(TEAMS * SLICES * 32 * 4);          // 16 KB

    k_zero<<<(NNZ_CAP + 255) / 256, 256, 0, stream>>>(csr, NNZ_CAP);
    k_zero<<<16, 256, 0, stream>>>((unsigned*)cnt, 4096);
    k_zero<<<16, 256, 0, stream>>>(flags, TEAMS * SLICES * 32);

    k_hist<<<(NNZ + 255) / 256, 256, 0, stream>>>(rec_rows, cnt);
    k_scan<<<1, 1024, 0, stream>>>(cnt, rowptr, cursor);
    k_fill<<<(NNZ + 255) / 256, 256, 0, stream>>>(rec_rows, rec_cols, rec_vals, cursor, csr);

    k_cvt<<<(R_OUT * N_RES / 8 + 255) / 256, 256, 0, stream>>>(B_w, Bwh, R_OUT * N_RES);
    k_cvt<<<(VOCAB * R_OUT / 8 + 255) / 256, 256, 0, stream>>>(A_w, Awh, VOCAB * R_OUT);

    k_steps<<<NWG, 256, 0, stream>>>(rowptr, csr, W_in, x, a, Hb, hx, flags);

    k_gemm1<<<dim3(R_OUT / 128, 2048 / 128), 512, 0, stream>>>(Hb, Bwh, Rbh);
    k_gemm2<<<dim3(2048 / 256, VOCAB / 128), 512, 0, stream>>>(Rbh, Awh, A_b, out);
}